// Round 1
// baseline (3155.904 us; speedup 1.0000x reference)
//
#include <hip/hip_runtime.h>
#include <math.h>

// ---------------------------------------------------------------------------
// FrameTransformer fp32 baseline.
// Layout convention: all activations (B,T,F) row-major, F fastest. B=4, T=F=1024.
// ---------------------------------------------------------------------------

#define NB 4
#define NT 1024
#define NF 1024

__device__ __forceinline__ float block_sum(float v) {
    __shared__ float sd[4];
    #pragma unroll
    for (int off = 32; off; off >>= 1) v += __shfl_down(v, off, 64);
    int lane = threadIdx.x & 63, wid = threadIdx.x >> 6;
    __syncthreads();
    if (lane == 0) sd[wid] = v;
    __syncthreads();
    return sd[0] + sd[1] + sd[2] + sd[3];
}

__device__ __forceinline__ float block_max(float v) {
    __shared__ float sd[4];
    #pragma unroll
    for (int off = 32; off; off >>= 1) v = fmaxf(v, __shfl_down(v, off, 64));
    int lane = threadIdx.x & 63, wid = threadIdx.x >> 6;
    __syncthreads();
    if (lane == 0) sd[wid] = v;
    __syncthreads();
    return fmaxf(fmaxf(sd[0], sd[1]), fmaxf(sd[2], sd[3]));
}

// ---------------------------------------------------------------------------
// Generic tiled GEMM:  C[M,N] (op) act( scale*(A·B(T) + bias + addT^T) )
//   BNT=true : B is [N,K] row-major (C = A·B^T)
//   BNT=false: B is [K,N] row-major (C = A·B)
//   ACT: 0 none, 1 relu, 2 square(relu)
//   ACCUM: C += v  (else C = v)
//   addT (optional): v += addT[n*ldt + m]  (transposed add, for rel-pos bias)
// All of M,N,K are multiples of 64/16 for every call site -> no bounds checks.
// ---------------------------------------------------------------------------
template<bool BNT, int ACT, bool ACCUM>
__global__ __launch_bounds__(256)
void gemm_k(const float* __restrict__ A, const float* __restrict__ B,
            float* __restrict__ C, int M, int N, int K,
            int lda, int ldb, int ldc,
            long long sAz, long long sBz, long long sCz,
            const float* __restrict__ bias,
            const float* __restrict__ addT, long long sTz, int ldt,
            float scale)
{
    A += (long long)blockIdx.z * sAz;
    B += (long long)blockIdx.z * sBz;
    C += (long long)blockIdx.z * sCz;
    if (addT) addT += (long long)blockIdx.z * sTz;

    __shared__ float As[16][65];
    __shared__ float Bs[16][65];

    const int tid = threadIdx.x;
    const int tx = tid & 15;   // n direction
    const int ty = tid >> 4;   // m direction
    const int m0 = blockIdx.y * 64;
    const int n0 = blockIdx.x * 64;

    float acc[4][4] = {};

    for (int k0 = 0; k0 < K; k0 += 16) {
        #pragma unroll
        for (int r = 0; r < 4; r++) {
            int idx = tid + r * 256;
            int m = idx >> 4, kk = idx & 15;
            As[kk][m] = A[(long long)(m0 + m) * lda + k0 + kk];
        }
        if constexpr (BNT) {
            #pragma unroll
            for (int r = 0; r < 4; r++) {
                int idx = tid + r * 256;
                int n = idx >> 4, kk = idx & 15;
                Bs[kk][n] = B[(long long)(n0 + n) * ldb + k0 + kk];
            }
        } else {
            #pragma unroll
            for (int r = 0; r < 4; r++) {
                int idx = tid + r * 256;
                int kk = idx >> 6, n = idx & 63;
                Bs[kk][n] = B[(long long)(k0 + kk) * ldb + n0 + n];
            }
        }
        __syncthreads();
        #pragma unroll
        for (int kk = 0; kk < 16; kk++) {
            float a[4], b[4];
            #pragma unroll
            for (int i = 0; i < 4; i++) a[i] = As[kk][ty + 16 * i];
            #pragma unroll
            for (int j = 0; j < 4; j++) b[j] = Bs[kk][tx + 16 * j];
            #pragma unroll
            for (int i = 0; i < 4; i++)
                #pragma unroll
                for (int j = 0; j < 4; j++)
                    acc[i][j] += a[i] * b[j];
        }
        __syncthreads();
    }

    #pragma unroll
    for (int i = 0; i < 4; i++) {
        int m = m0 + ty + 16 * i;
        #pragma unroll
        for (int j = 0; j < 4; j++) {
            int n = n0 + tx + 16 * j;
            float v = acc[i][j];
            if (bias) v += bias[n];
            if (addT) v += addT[(long long)n * ldt + m];
            v *= scale;
            if (ACT == 1) v = fmaxf(v, 0.f);
            else if (ACT == 2) { v = fmaxf(v, 0.f); v = v * v; }
            long long ci = (long long)m * ldc + n;
            if (ACCUM) C[ci] += v; else C[ci] = v;
        }
    }
}

// ---------------------------------------------------------------------------
// LayerNorm over last dim (1024). One block per row, 256 threads * float4.
// ---------------------------------------------------------------------------
__global__ __launch_bounds__(256)
void ln_k(const float* __restrict__ in, float* __restrict__ out,
          const float* __restrict__ g, const float* __restrict__ b)
{
    long long row = blockIdx.x;
    const float4* ip = (const float4*)(in + row * 1024);
    float4* op = (float4*)(out + row * 1024);
    int tid = threadIdx.x;
    float4 v = ip[tid];
    float s = v.x + v.y + v.z + v.w;
    s = block_sum(s);
    float mean = s * (1.f / 1024.f);
    float dx = v.x - mean, dy = v.y - mean, dz = v.z - mean, dw = v.w - mean;
    float s2 = dx * dx + dy * dy + dz * dz + dw * dw;
    s2 = block_sum(s2);
    float inv = rsqrtf(s2 * (1.f / 1024.f) + 1e-5f);
    float4 gg = ((const float4*)g)[tid];
    float4 bb = ((const float4*)b)[tid];
    float4 o;
    o.x = dx * inv * gg.x + bb.x;
    o.y = dy * inv * gg.y + bb.y;
    o.z = dz * inv * gg.z + bb.z;
    o.w = dw * inv * gg.w + bb.w;
    op[tid] = o;
}

// Softmax over last dim (1024), in place. One block per row.
__global__ __launch_bounds__(256)
void softmax_k(float* __restrict__ S)
{
    long long row = blockIdx.x;
    float4* p = (float4*)(S + row * 1024);
    int tid = threadIdx.x;
    float4 v = p[tid];
    float m = fmaxf(fmaxf(v.x, v.y), fmaxf(v.z, v.w));
    m = block_max(m);
    v.x = expf(v.x - m); v.y = expf(v.y - m);
    v.z = expf(v.z - m); v.w = expf(v.w - m);
    float s = v.x + v.y + v.z + v.w;
    s = block_sum(s);
    float r = 1.f / s;
    v.x *= r; v.y *= r; v.z *= r; v.w *= r;
    p[tid] = v;
}

// ---------------------------------------------------------------------------
// Input projection: X[b,t,f] = w0*src[b,0,f,t] + w1*src[b,1,f,t]  (tiled transpose)
// ---------------------------------------------------------------------------
__global__ __launch_bounds__(256)
void inproj_k(const float* __restrict__ src, const float* __restrict__ inw,
              float* __restrict__ X)
{
    __shared__ float tile[32][33];
    int b = blockIdx.z;
    int f0 = blockIdx.y * 32, t0 = blockIdx.x * 32;
    float w0 = inw[0], w1 = inw[1];
    for (int r = threadIdx.y; r < 32; r += 8) {
        int f = f0 + r, t = t0 + threadIdx.x;
        float s0 = src[(((long long)b * 2 + 0) * 1025 + f) * 1024 + t];
        float s1 = src[(((long long)b * 2 + 1) * 1025 + f) * 1024 + t];
        tile[r][threadIdx.x] = w0 * s0 + w1 * s1;
    }
    __syncthreads();
    for (int r = threadIdx.y; r < 32; r += 8)
        X[((long long)b * 1024 + t0 + r) * 1024 + f0 + threadIdx.x] = tile[threadIdx.x][r];
}

// GLU: X[row,f] += G[row,f] * sigmoid(G[row,1024+f])
__global__ __launch_bounds__(256)
void glu_k(const float* __restrict__ G, float* __restrict__ X)
{
    int idx = blockIdx.x * 256 + threadIdx.x;
    int f = idx & 1023;
    long long row = idx >> 10;
    float a = G[row * 2048 + f];
    float s = G[row * 2048 + 1024 + f];
    X[idx] += a * (1.f / (1.f + expf(-s)));
}

// Depthwise conv along f (contiguous axis), channels = t, ksize 11, pad 5.
__global__ __launch_bounds__(256)
void dconvF_k(const float* __restrict__ in, float* __restrict__ out,
              const float* __restrict__ w)
{
    int idx = blockIdx.x * 256 + threadIdx.x;
    int f = idx & 1023;
    int bt = idx >> 10;
    int t = bt & 1023;
    const float* row = in + (long long)bt * 1024;
    const float* wr = w + t * 11;
    float acc = 0.f;
    #pragma unroll
    for (int k = 0; k < 11; k++) {
        int ff = f + k - 5;
        if (ff >= 0 && ff < 1024) acc += row[ff] * wr[k];
    }
    out[idx] = acc;
}

// Depthwise conv along t (strided axis), channels = f, ksize 7, pad 3, opt bias.
__global__ __launch_bounds__(256)
void dconvT_k(const float* __restrict__ in, float* __restrict__ out,
              const float* __restrict__ w, const float* __restrict__ bias)
{
    int idx = blockIdx.x * 256 + threadIdx.x;
    int f = idx & 1023;
    int bt = idx >> 10;
    int t = bt & 1023;
    int b = bt >> 10;
    const float* wr = w + f * 7;
    float acc = bias ? bias[f] : 0.f;
    #pragma unroll
    for (int k = 0; k < 7; k++) {
        int tt = t + k - 3;
        if (tt >= 0 && tt < 1024)
            acc += in[(((long long)b << 10) + tt) * 1024 + f] * wr[k];
    }
    out[idx] = acc;
}

// Output: y[b,o,f,t] = clip(ow[o,0]*src0 + ow[o,1]*src1 + ow[o,2]*X[b,t,f], 0, 6)/6
// plus duplicate of f=1023 row into f=1024.
__global__ __launch_bounds__(256)
void out_k(const float* __restrict__ src, const float* __restrict__ X,
           const float* __restrict__ ow, float* __restrict__ out)
{
    __shared__ float tile[32][33];
    int b = blockIdx.z;
    int f0 = blockIdx.y * 32, t0 = blockIdx.x * 32;
    for (int r = threadIdx.y; r < 32; r += 8)
        tile[r][threadIdx.x] = X[((long long)b * 1024 + t0 + r) * 1024 + f0 + threadIdx.x];
    __syncthreads();
    float w00 = ow[0], w01 = ow[1], w02 = ow[2];
    float w10 = ow[3], w11 = ow[4], w12 = ow[5];
    for (int r = threadIdx.y; r < 32; r += 8) {
        int f = f0 + r, t = t0 + threadIdx.x;
        float s0 = src[(((long long)b * 2 + 0) * 1025 + f) * 1024 + t];
        float s1 = src[(((long long)b * 2 + 1) * 1025 + f) * 1024 + t];
        float xv = tile[threadIdx.x][r];
        float v0 = fminf(fmaxf(w00 * s0 + w01 * s1 + w02 * xv, 0.f), 6.f) * (1.f / 6.f);
        float v1 = fminf(fmaxf(w10 * s0 + w11 * s1 + w12 * xv, 0.f), 6.f) * (1.f / 6.f);
        out[(((long long)b * 2 + 0) * 1025 + f) * 1024 + t] = v0;
        out[(((long long)b * 2 + 1) * 1025 + f) * 1024 + t] = v1;
        if (f == 1023) {
            out[(((long long)b * 2 + 0) * 1025 + 1024) * 1024 + t] = v0;
            out[(((long long)b * 2 + 1) * 1025 + 1024) * 1024 + t] = v1;
        }
    }
}

// ---------------------------------------------------------------------------
extern "C" void kernel_launch(void* const* d_in, const int* in_sizes, int n_in,
                              void* d_out, int out_size, void* d_ws, size_t ws_size,
                              hipStream_t stream)
{
    const float* src    = (const float*)d_in[0];
    const float* in_w   = (const float*)d_in[1];
    const float* ln1_g  = (const float*)d_in[2];
    const float* ln1_b  = (const float*)d_in[3];
    const float* glu_w  = (const float*)d_in[4];
    const float* ln2_g  = (const float*)d_in[5];
    const float* ln2_b  = (const float*)d_in[6];
    const float* c1L_dw = (const float*)d_in[7];
    const float* c1L_pw = (const float*)d_in[8];
    const float* c1R_dw = (const float*)d_in[9];
    const float* c1R_pw = (const float*)d_in[10];
    const float* ln3_g  = (const float*)d_in[11];
    const float* ln3_b  = (const float*)d_in[12];
    const float* c1M_dw = (const float*)d_in[13];
    const float* c1M_pw = (const float*)d_in[14];
    const float* ln4_g  = (const float*)d_in[15];
    const float* ln4_b  = (const float*)d_in[16];
    const float* q_w    = (const float*)d_in[17];
    const float* q_b    = (const float*)d_in[18];
    const float* qc_w   = (const float*)d_in[19];
    const float* qc_b   = (const float*)d_in[20];
    const float* k_w    = (const float*)d_in[21];
    const float* k_b    = (const float*)d_in[22];
    const float* v_w    = (const float*)d_in[23];
    const float* v_b    = (const float*)d_in[24];
    const float* o_w    = (const float*)d_in[25];
    const float* o_b    = (const float*)d_in[26];
    const float* er     = (const float*)d_in[27];
    const float* ln5_g  = (const float*)d_in[28];
    const float* ln5_b  = (const float*)d_in[29];
    const float* c2_w   = (const float*)d_in[30];
    const float* c3_w   = (const float*)d_in[31];
    const float* out_w  = (const float*)d_in[32];
    float* out = (float*)d_out;

    const long long M1 = 1024LL * 1024LL;   // one (T,F) plane, in floats
    float* ws = (float*)d_ws;
    if (ws_size < (size_t)(44 * M1 * sizeof(float))) return;  // need 176 MB

    float* X  = ws;            // (B,T,F) residual
    float* H  = ws + 4 * M1;   // (B,T,F) temp (ln outputs, attn out)
    float* T1 = ws + 8 * M1;   // (B,T,F) temp (dconv outs, qkv pre-conv)
    float* SB = ws + 12 * M1;  // (B,1024,1024) hL+hR sum
    float* Q  = ws + 16 * M1;
    float* Kb = ws + 20 * M1;
    float* Vb = ws + 24 * M1;
    float* G  = ws + 28 * M1;  // (B,T,2048) glu / ffn mid
    float* Pb = ws + 36 * M1;  // per-batch (4,T,1024) rel-pos
    float* Sb = ws + 40 * M1;  // per-batch (4,T,T) scores

    const dim3 blk256(256);
    const dim3 tgrid(32, 32, NB);
    const dim3 tblk(32, 8);
    const int EW = 16384;      // 4M elems / 256

    // 1. x = einsum('bcft,c->btf', src[:,:, :1024], in_w)
    inproj_k<<<tgrid, tblk, 0, stream>>>(src, in_w, X);
    // 2. h = ln1(x)
    ln_k<<<4096, blk256, 0, stream>>>(X, H, ln1_g, ln1_b);
    // 3. g = h @ glu_w.T    (4096 x 2048 x 1024)
    gemm_k<true, 0, false><<<dim3(32, 64, 1), blk256, 0, stream>>>(
        H, glu_w, G, 4096, 2048, 1024, 1024, 1024, 2048,
        0, 0, 0, nullptr, nullptr, 0, 0, 1.f);
    // 4. x += g[:, :1024] * sigmoid(g[:, 1024:])
    glu_k<<<EW, blk256, 0, stream>>>(G, X);
    // 5. h = ln2(x)
    ln_k<<<4096, blk256, 0, stream>>>(X, H, ln2_g, ln2_b);
    // 6-7. hL = relu(c1L_pw @ dconvF(h))   per batch: SB[b][o][l]
    dconvF_k<<<EW, blk256, 0, stream>>>(H, T1, c1L_dw);
    gemm_k<false, 1, false><<<dim3(16, 16, NB), blk256, 0, stream>>>(
        c1L_pw, T1, SB, 1024, 1024, 1024, 1024, 1024, 1024,
        0, M1, M1, nullptr, nullptr, 0, 0, 1.f);
    // 8-9. SB += relu(dconvT(h) @ c1R_pw^T)  (cols 0..511)
    dconvT_k<<<EW, blk256, 0, stream>>>(H, T1, c1R_dw, nullptr);
    gemm_k<true, 1, true><<<dim3(8, 64, 1), blk256, 0, stream>>>(
        T1, c1R_pw, SB, 4096, 512, 1024, 1024, 1024, 1024,
        0, 0, 0, nullptr, nullptr, 0, 0, 1.f);
    // 10. h = ln3(SB)
    ln_k<<<4096, blk256, 0, stream>>>(SB, H, ln3_g, ln3_b);
    // 11-12. x += dconvT(h) @ c1M_pw^T
    dconvT_k<<<EW, blk256, 0, stream>>>(H, T1, c1M_dw, nullptr);
    gemm_k<true, 0, true><<<dim3(16, 64, 1), blk256, 0, stream>>>(
        T1, c1M_pw, X, 4096, 1024, 1024, 1024, 1024, 1024,
        0, 0, 0, nullptr, nullptr, 0, 0, 1.f);
    // 13. h = ln4(x)
    ln_k<<<4096, blk256, 0, stream>>>(X, H, ln4_g, ln4_b);
    // 14. Q/K/V = qc_conv(h @ W^T + b) + qc_b
    gemm_k<true, 0, false><<<dim3(16, 64, 1), blk256, 0, stream>>>(
        H, q_w, T1, 4096, 1024, 1024, 1024, 1024, 1024,
        0, 0, 0, q_b, nullptr, 0, 0, 1.f);
    dconvT_k<<<EW, blk256, 0, stream>>>(T1, Q, qc_w, qc_b);
    gemm_k<true, 0, false><<<dim3(16, 64, 1), blk256, 0, stream>>>(
        H, k_w, T1, 4096, 1024, 1024, 1024, 1024, 1024,
        0, 0, 0, k_b, nullptr, 0, 0, 1.f);
    dconvT_k<<<EW, blk256, 0, stream>>>(T1, Kb, qc_w, qc_b);
    gemm_k<true, 0, false><<<dim3(16, 64, 1), blk256, 0, stream>>>(
        H, v_w, T1, 4096, 1024, 1024, 1024, 1024, 1024,
        0, 0, 0, v_b, nullptr, 0, 0, 1.f);
    dconvT_k<<<EW, blk256, 0, stream>>>(T1, Vb, qc_w, qc_b);

    // 15-18. attention, per batch; H becomes attn-out in (B,T,F) layout
    const float iscale = 0.03125f;  // 1/sqrt(1024)
    for (int b = 0; b < NB; b++) {
        const float* Qx = Q + (long long)b * M1;
        const float* Kx = Kb + (long long)b * M1;
        const float* Vx = Vb + (long long)b * M1;
        float* AOx = H + (long long)b * M1;
        // P[band][t][j] = sum_d Q[b,t,band*256+d] * er[d,j]
        gemm_k<false, 0, false><<<dim3(16, 16, 4), blk256, 0, stream>>>(
            Qx, er, Pb, 1024, 1024, 256, 1024, 1024, 1024,
            256, 0, M1, nullptr, nullptr, 0, 0, 1.f);
        // S[band][i][j] = (sum_d Q[i,d]K[j,d] + P[band][j][i]) / 32
        gemm_k<true, 0, false><<<dim3(16, 16, 4), blk256, 0, stream>>>(
            Qx, Kx, Sb, 1024, 1024, 256, 1024, 1024, 1024,
            256, 256, M1, nullptr, Pb, M1, 1024, iscale);
        softmax_k<<<4096, blk256, 0, stream>>>(Sb);
        // AO[b,t,band*256+d] = sum_j S[band][t][j] * V[b,j,band*256+d]
        gemm_k<false, 0, false><<<dim3(4, 16, 4), blk256, 0, stream>>>(
            Sb, Vx, AOx, 1024, 256, 1024, 1024, 1024, 1024,
            M1, 256, 256, nullptr, nullptr, 0, 0, 1.f);
    }
    // 19. x += AO @ o_w^T + o_b
    gemm_k<true, 0, true><<<dim3(16, 64, 1), blk256, 0, stream>>>(
        H, o_w, X, 4096, 1024, 1024, 1024, 1024, 1024,
        0, 0, 0, o_b, nullptr, 0, 0, 1.f);
    // 20. h = ln5(x)
    ln_k<<<4096, blk256, 0, stream>>>(X, H, ln5_g, ln5_b);
    // 21. mid = relu(h @ c2_w^T)^2
    gemm_k<true, 2, false><<<dim3(32, 64, 1), blk256, 0, stream>>>(
        H, c2_w, G, 4096, 2048, 1024, 1024, 1024, 2048,
        0, 0, 0, nullptr, nullptr, 0, 0, 1.f);
    // 22. x += mid @ c3_w^T
    gemm_k<true, 0, true><<<dim3(16, 64, 1), blk256, 0, stream>>>(
        G, c3_w, X, 4096, 1024, 2048, 2048, 2048, 1024,
        0, 0, 0, nullptr, nullptr, 0, 0, 1.f);
    // 23. final output (+ duplicated last freq row)
    out_k<<<tgrid, tblk, 0, stream>>>(src, X, out_w, out);
}

// Round 2
// 1003.999 us; speedup vs baseline: 3.1433x; 3.1433x over previous
//
#include <hip/hip_runtime.h>
#include <math.h>

// ---------------------------------------------------------------------------
// FrameTransformer — bf16 MFMA round.
// Activations (B,T,F) row-major, B=4, T=F=1024. Residual X fp32; GEMM
// operands bf16; all GEMMs NT-form (A[M,K] · W[N,K]^T) via transposed
// producers for c1L-conv output, V, and er.
// ---------------------------------------------------------------------------

typedef unsigned short u16;
typedef __attribute__((ext_vector_type(4))) float floatx4;
typedef __attribute__((ext_vector_type(8))) short short8;

#define NB 4
static const long long M1 = 1024LL * 1024LL;

__device__ __forceinline__ float bf2f(u16 h) {
    union { unsigned int u; float f; } v;
    v.u = ((unsigned int)h) << 16;
    return v.f;
}
__device__ __forceinline__ u16 f2bf(float x) {
    union { float f; unsigned int u; } v;
    v.f = x;
    unsigned int r = (v.u + 0x7FFFu + ((v.u >> 16) & 1u)) >> 16;
    return (u16)r;
}

// async 16B global->LDS (per-lane global addr; LDS dest = base + lane*16)
__device__ __forceinline__ void async_cp16(const u16* g, u16* lds) {
    __builtin_amdgcn_global_load_lds(
        (const __attribute__((address_space(1))) unsigned int*)g,
        (__attribute__((address_space(3))) unsigned int*)lds, 16, 0, 0);
}

__device__ __forceinline__ float block_sum(float v) {
    __shared__ float sd[4];
    #pragma unroll
    for (int off = 32; off; off >>= 1) v += __shfl_down(v, off, 64);
    int lane = threadIdx.x & 63, wid = threadIdx.x >> 6;
    __syncthreads();
    if (lane == 0) sd[wid] = v;
    __syncthreads();
    return sd[0] + sd[1] + sd[2] + sd[3];
}
__device__ __forceinline__ float block_max(float v) {
    __shared__ float sd[4];
    #pragma unroll
    for (int off = 32; off; off >>= 1) v = fmaxf(v, __shfl_down(v, off, 64));
    int lane = threadIdx.x & 63, wid = threadIdx.x >> 6;
    __syncthreads();
    if (lane == 0) sd[wid] = v;
    __syncthreads();
    return fmaxf(fmaxf(sd[0], sd[1]), fmaxf(sd[2], sd[3]));
}

// ---------------------------------------------------------------------------
// bf16 NT GEMM: C[M,N] (op)= act( scale*(A·B^T + bias + addT^T) )
// A [M,K] bf16 row-major, B [N,K] bf16 row-major. 128x128 tile, BK=32.
// 256 thr = 4 waves (2x2), each wave 64x64 = 4x4 MFMA 16x16x32 tiles.
// ACT: 0 none, 1 relu, 2 relu^2.  ACCUM: fp32 C += v.  OBF: write bf16.
// All M,N multiples of 128; K multiple of 32. Strides in elements.
// ---------------------------------------------------------------------------
template<int ACT, bool ACCUM, bool OBF>
__global__ __launch_bounds__(256)
void gemm_bf(const u16* __restrict__ A, const u16* __restrict__ B,
             void* __restrict__ Cv, int K, int lda, int ldb, int ldc,
             long long sAz, long long sBz, long long sCz,
             const float* __restrict__ bias,
             const float* __restrict__ addT, long long sTz, int ldt,
             float scale)
{
    A += (long long)blockIdx.z * sAz;
    B += (long long)blockIdx.z * sBz;
    if (addT) addT += (long long)blockIdx.z * sTz;
    const long long zc = (long long)blockIdx.z * sCz;

    __shared__ u16 As[128 * 32];   // [row][kk], 64B rows
    __shared__ u16 Bs[128 * 32];

    const int tid  = threadIdx.x;
    const int lane = tid & 63;
    const int w    = tid >> 6;
    const int wm   = (w >> 1) * 64;
    const int wn   = (w & 1) * 64;
    const int m0   = blockIdx.y * 128;
    const int n0   = blockIdx.x * 128;

    // staging geometry: wave w, round r covers rows r*64 + w*16 .. +16
    const int srow = (lane >> 2);          // 0..15 within 16-row group
    const int skq  = (lane & 3) * 8;       // k element offset (8 bf16 = 16B)

    floatx4 acc[4][4];
    #pragma unroll
    for (int i = 0; i < 4; i++)
        #pragma unroll
        for (int j = 0; j < 4; j++)
            acc[i][j] = floatx4{0.f, 0.f, 0.f, 0.f};

    for (int k0 = 0; k0 < K; k0 += 32) {
        #pragma unroll
        for (int r = 0; r < 2; r++) {
            const int rowbase = r * 64 + w * 16;
            async_cp16(A + (long long)(m0 + rowbase + srow) * lda + k0 + skq,
                       &As[rowbase * 32]);
            async_cp16(B + (long long)(n0 + rowbase + srow) * ldb + k0 + skq,
                       &Bs[rowbase * 32]);
        }
        __syncthreads();   // drains vmcnt(0) before barrier

        short8 a[4], b[4];
        const int fr = (lane & 15);        // row/col within 16
        const int fq = (lane >> 4) * 8;    // k offset within 32
        #pragma unroll
        for (int i = 0; i < 4; i++)
            a[i] = *(const short8*)&As[(wm + i * 16 + fr) * 32 + fq];
        #pragma unroll
        for (int j = 0; j < 4; j++)
            b[j] = *(const short8*)&Bs[(wn + j * 16 + fr) * 32 + fq];
        #pragma unroll
        for (int i = 0; i < 4; i++)
            #pragma unroll
            for (int j = 0; j < 4; j++)
                acc[i][j] = __builtin_amdgcn_mfma_f32_16x16x32_bf16(
                    a[i], b[j], acc[i][j], 0, 0, 0);
        __syncthreads();
    }

    // epilogue: C/D layout col=lane&15, row=(lane>>4)*4+reg
    float* Cf = (float*)Cv;
    u16*  Cb  = (u16*)Cv;
    const int cn    = n0 + wn + (lane & 15);
    const int rbase = m0 + wm + (lane >> 4) * 4;
    float bj[4];
    #pragma unroll
    for (int j = 0; j < 4; j++) bj[j] = bias ? bias[cn + j * 16] : 0.f;

    #pragma unroll
    for (int i = 0; i < 4; i++) {
        #pragma unroll
        for (int r = 0; r < 4; r++) {
            const int m = rbase + i * 16 + r;
            #pragma unroll
            for (int j = 0; j < 4; j++) {
                const int n = cn + j * 16;
                float v = acc[i][j][r] + bj[j];
                if (addT) v += addT[(long long)n * ldt + m];
                v *= scale;
                if (ACT == 1) v = fmaxf(v, 0.f);
                else if (ACT == 2) { v = fmaxf(v, 0.f); v = v * v; }
                const long long ci = zc + (long long)m * ldc + n;
                if (OBF)        Cb[ci] = f2bf(v);
                else if (ACCUM) Cf[ci] += v;
                else            Cf[ci] = v;
            }
        }
    }
}

// ---------------------------------------------------------------------------
// LayerNorm over last dim 1024: fp32 in -> bf16 out. One block/row.
// ---------------------------------------------------------------------------
__global__ __launch_bounds__(256)
void ln_bf_k(const float* __restrict__ in, u16* __restrict__ out,
             const float* __restrict__ g, const float* __restrict__ b)
{
    long long row = blockIdx.x;
    const float4* ip = (const float4*)(in + (row << 10));
    int tid = threadIdx.x;
    float4 v = ip[tid];
    float s = v.x + v.y + v.z + v.w;
    s = block_sum(s);
    float mean = s * (1.f / 1024.f);
    float dx = v.x - mean, dy = v.y - mean, dz = v.z - mean, dw = v.w - mean;
    float s2 = dx * dx + dy * dy + dz * dz + dw * dw;
    s2 = block_sum(s2);
    float inv = rsqrtf(s2 * (1.f / 1024.f) + 1e-5f);
    float4 gg = ((const float4*)g)[tid];
    float4 bb = ((const float4*)b)[tid];
    ushort4 o;
    o.x = f2bf(dx * inv * gg.x + bb.x);
    o.y = f2bf(dy * inv * gg.y + bb.y);
    o.z = f2bf(dz * inv * gg.z + bb.z);
    o.w = f2bf(dw * inv * gg.w + bb.w);
    ((ushort4*)(out + (row << 10)))[tid] = o;
}

// Softmax over last dim 1024, bf16 in place. One block/row.
__global__ __launch_bounds__(256)
void softmax_bf_k(u16* __restrict__ S)
{
    long long row = blockIdx.x;
    u16* p = S + (row << 10);
    int tid = threadIdx.x;
    ushort4 u = ((ushort4*)p)[tid];
    float x0 = bf2f(u.x), x1 = bf2f(u.y), x2 = bf2f(u.z), x3 = bf2f(u.w);
    float m = fmaxf(fmaxf(x0, x1), fmaxf(x2, x3));
    m = block_max(m);
    x0 = expf(x0 - m); x1 = expf(x1 - m); x2 = expf(x2 - m); x3 = expf(x3 - m);
    float s = x0 + x1 + x2 + x3;
    s = block_sum(s);
    float r = 1.f / s;
    u.x = f2bf(x0 * r); u.y = f2bf(x1 * r); u.z = f2bf(x2 * r); u.w = f2bf(x3 * r);
    ((ushort4*)p)[tid] = u;
}

// ---------------------------------------------------------------------------
// Input projection: X[b,t,f] = w0*src[b,0,f,t] + w1*src[b,1,f,t]  (fp32)
// ---------------------------------------------------------------------------
__global__ __launch_bounds__(256)
void inproj_k(const float* __restrict__ src, const float* __restrict__ inw,
              float* __restrict__ X)
{
    __shared__ float tile[32][33];
    int b = blockIdx.z;
    int f0 = blockIdx.y * 32, t0 = blockIdx.x * 32;
    float w0 = inw[0], w1 = inw[1];
    for (int r = threadIdx.y; r < 32; r += 8) {
        int f = f0 + r, t = t0 + threadIdx.x;
        float s0 = src[(((long long)b * 2 + 0) * 1025 + f) * 1024 + t];
        float s1 = src[(((long long)b * 2 + 1) * 1025 + f) * 1024 + t];
        tile[r][threadIdx.x] = w0 * s0 + w1 * s1;
    }
    __syncthreads();
    for (int r = threadIdx.y; r < 32; r += 8)
        X[((long long)b * 1024 + t0 + r) * 1024 + f0 + threadIdx.x] = tile[threadIdx.x][r];
}

// GLU: X[row,f] += G[row,f] * sigmoid(G[row,1024+f])   (G fp32)
__global__ __launch_bounds__(256)
void glu_k(const float* __restrict__ G, float* __restrict__ X)
{
    int idx = blockIdx.x * 256 + threadIdx.x;
    int f = idx & 1023;
    long long row = idx >> 10;
    float a = G[row * 2048 + f];
    float s = G[row * 2048 + 1024 + f];
    X[idx] += a * (1.f / (1.f + expf(-s)));
}

// Depthwise conv along f (contiguous), channels=t, k=11 pad 5, bf16 in,
// TRANSPOSED bf16 out: out[b][f][t].
__global__ __launch_bounds__(256)
void dconvF_t_k(const u16* __restrict__ in, u16* __restrict__ out,
                const float* __restrict__ w)
{
    __shared__ float itile[32][44];
    __shared__ float otile[32][33];
    int b = blockIdx.z, t0 = blockIdx.y * 32, f0 = blockIdx.x * 32;
    int tx = threadIdx.x & 31, ty = threadIdx.x >> 5;
    for (int r = ty; r < 32; r += 8)
        for (int c = tx; c < 42; c += 32) {
            int f = f0 - 5 + c;
            itile[r][c] = (f >= 0 && f < 1024)
                ? bf2f(in[((long long)(b * 1024 + t0 + r)) * 1024 + f]) : 0.f;
        }
    __syncthreads();
    for (int r = ty; r < 32; r += 8) {
        const float* wr = w + (t0 + r) * 11;
        float acc = 0.f;
        #pragma unroll
        for (int k = 0; k < 11; k++) acc += itile[r][tx + k] * wr[k];
        otile[tx][r] = acc;
    }
    __syncthreads();
    for (int r = ty; r < 32; r += 8)
        out[((long long)(b * 1024 + f0 + r)) * 1024 + t0 + tx] = f2bf(otile[r][tx]);
}

// Depthwise conv along t (strided), channels=f, k=7 pad 3, bf16 in/out (B,T,F).
__global__ __launch_bounds__(256)
void dconvT_bf_k(const u16* __restrict__ in, u16* __restrict__ out,
                 const float* __restrict__ w, const float* __restrict__ bias)
{
    int idx = blockIdx.x * 256 + threadIdx.x;
    int f = idx & 1023;
    int bt = idx >> 10;
    int t = bt & 1023;
    int b = bt >> 10;
    const float* wr = w + f * 7;
    float acc = bias ? bias[f] : 0.f;
    #pragma unroll
    for (int k = 0; k < 7; k++) {
        int tt = t + k - 3;
        if (tt >= 0 && tt < 1024)
            acc += bf2f(in[(((long long)b << 10) + tt) * 1024 + f]) * wr[k];
    }
    out[idx] = f2bf(acc);
}

// Depthwise conv along t, channels=f, k=7 pad 3 + bias, TRANSPOSED out[b][f][t].
__global__ __launch_bounds__(256)
void dconvT_t_k(const u16* __restrict__ in, u16* __restrict__ out,
                const float* __restrict__ w, const float* __restrict__ bias)
{
    __shared__ float itile[38][32];
    __shared__ float otile[32][33];
    int b = blockIdx.z, t0 = blockIdx.y * 32, f0 = blockIdx.x * 32;
    int tx = threadIdx.x & 31, ty = threadIdx.x >> 5;
    for (int i = threadIdx.x; i < 38 * 32; i += 256) {
        int r = i >> 5, c = i & 31;
        int t = t0 - 3 + r;
        itile[r][c] = (t >= 0 && t < 1024)
            ? bf2f(in[((long long)(b * 1024 + t)) * 1024 + f0 + c]) : 0.f;
    }
    __syncthreads();
    for (int r = ty; r < 32; r += 8) {
        const float* wr = w + (f0 + tx) * 7;
        float acc = bias[f0 + tx];
        #pragma unroll
        for (int k = 0; k < 7; k++) acc += itile[r + k][tx] * wr[k];
        otile[tx][r] = acc;
    }
    __syncthreads();
    for (int r = ty; r < 32; r += 8)
        out[((long long)(b * 1024 + f0 + r)) * 1024 + t0 + tx] = f2bf(otile[r][tx]);
}

// fp32 -> bf16 cast
__global__ __launch_bounds__(256)
void cast_k(const float* __restrict__ in, u16* __restrict__ out, int n)
{
    int i = blockIdx.x * 256 + threadIdx.x;
    if (i < n) out[i] = f2bf(in[i]);
}

// er (256,1024) -> ert (1024,256) bf16
__global__ __launch_bounds__(256)
void ercast_k(const float* __restrict__ er, u16* __restrict__ ert)
{
    int idx = blockIdx.x * 256 + threadIdx.x;
    int j = idx >> 8, d = idx & 255;
    ert[idx] = f2bf(er[d * 1024 + j]);
}

// Output head (fp32), incl. duplicated last freq row.
__global__ __launch_bounds__(256)
void out_k(const float* __restrict__ src, const float* __restrict__ X,
           const float* __restrict__ ow, float* __restrict__ out)
{
    __shared__ float tile[32][33];
    int b = blockIdx.z;
    int f0 = blockIdx.y * 32, t0 = blockIdx.x * 32;
    for (int r = threadIdx.y; r < 32; r += 8)
        tile[r][threadIdx.x] = X[((long long)b * 1024 + t0 + r) * 1024 + f0 + threadIdx.x];
    __syncthreads();
    float w00 = ow[0], w01 = ow[1], w02 = ow[2];
    float w10 = ow[3], w11 = ow[4], w12 = ow[5];
    for (int r = threadIdx.y; r < 32; r += 8) {
        int f = f0 + r, t = t0 + threadIdx.x;
        float s0 = src[(((long long)b * 2 + 0) * 1025 + f) * 1024 + t];
        float s1 = src[(((long long)b * 2 + 1) * 1025 + f) * 1024 + t];
        float xv = tile[threadIdx.x][r];
        float v0 = fminf(fmaxf(w00 * s0 + w01 * s1 + w02 * xv, 0.f), 6.f) * (1.f / 6.f);
        float v1 = fminf(fmaxf(w10 * s0 + w11 * s1 + w12 * xv, 0.f), 6.f) * (1.f / 6.f);
        out[(((long long)b * 2 + 0) * 1025 + f) * 1024 + t] = v0;
        out[(((long long)b * 2 + 1) * 1025 + f) * 1024 + t] = v1;
        if (f == 1023) {
            out[(((long long)b * 2 + 0) * 1025 + 1024) * 1024 + t] = v0;
            out[(((long long)b * 2 + 1) * 1025 + 1024) * 1024 + t] = v1;
        }
    }
}

// ---------------------------------------------------------------------------
extern "C" void kernel_launch(void* const* d_in, const int* in_sizes, int n_in,
                              void* d_out, int out_size, void* d_ws, size_t ws_size,
                              hipStream_t stream)
{
    const float* src    = (const float*)d_in[0];
    const float* in_w   = (const float*)d_in[1];
    const float* ln1_g  = (const float*)d_in[2];
    const float* ln1_b  = (const float*)d_in[3];
    const float* glu_w  = (const float*)d_in[4];
    const float* ln2_g  = (const float*)d_in[5];
    const float* ln2_b  = (const float*)d_in[6];
    const float* c1L_dw = (const float*)d_in[7];
    const float* c1L_pw = (const float*)d_in[8];
    const float* c1R_dw = (const float*)d_in[9];
    const float* c1R_pw = (const float*)d_in[10];
    const float* ln3_g  = (const float*)d_in[11];
    const float* ln3_b  = (const float*)d_in[12];
    const float* c1M_dw = (const float*)d_in[13];
    const float* c1M_pw = (const float*)d_in[14];
    const float* ln4_g  = (const float*)d_in[15];
    const float* ln4_b  = (const float*)d_in[16];
    const float* q_w    = (const float*)d_in[17];
    const float* q_b    = (const float*)d_in[18];
    const float* qc_w   = (const float*)d_in[19];
    const float* qc_b   = (const float*)d_in[20];
    const float* k_w    = (const float*)d_in[21];
    const float* k_b    = (const float*)d_in[22];
    const float* v_w    = (const float*)d_in[23];
    const float* v_b    = (const float*)d_in[24];
    const float* o_w    = (const float*)d_in[25];
    const float* o_b    = (const float*)d_in[26];
    const float* er     = (const float*)d_in[27];
    const float* ln5_g  = (const float*)d_in[28];
    const float* ln5_b  = (const float*)d_in[29];
    const float* c2_w   = (const float*)d_in[30];
    const float* c3_w   = (const float*)d_in[31];
    const float* out_w  = (const float*)d_in[32];
    float* out = (float*)d_out;

    const size_t MB = 1ull << 20;
    if (ws_size < 170 * MB) return;
    char* wsb = (char*)d_ws;
    float* X   = (float*)(wsb + 0);        // 16 MB fp32 residual
    float* SB  = (float*)(wsb + 16 * MB);  // 16 MB fp32 hL+hR
    float* G   = (float*)(wsb + 32 * MB);  // 32 MB fp32 glu out
    u16*  Gbf  = (u16*) (wsb + 32 * MB);   // reuse: 16 MB bf16 ffn mid
    float* Pb  = (float*)(wsb + 64 * MB);  // 16 MB fp32 rel-pos (per batch)
    u16* Hbf   = (u16*)(wsb + 80 * MB);    // 8 MB ln outputs
    u16* T1bf  = (u16*)(wsb + 88 * MB);    // 8 MB dconv/qkv-pre/AO
    u16* T2bf  = (u16*)(wsb + 96 * MB);    // 8 MB transposed dconvF out
    u16* Qbf   = (u16*)(wsb + 104 * MB);
    u16* Kbf   = (u16*)(wsb + 112 * MB);
    u16* Vt    = (u16*)(wsb + 120 * MB);   // V transposed (B,F,T)
    u16* Sbf   = (u16*)(wsb + 128 * MB);   // 8 MB scores (per batch, 4 bands)
    u16* W0    = (u16*)(wsb + 136 * MB);   // bf16 weights

    u16* glu_wb  = W0;
    u16* c1L_pwb = glu_wb  + 2097152;
    u16* c1R_pwb = c1L_pwb + 1048576;
    u16* c1M_pwb = c1R_pwb + 524288;
    u16* q_wb    = c1M_pwb + 1048576;
    u16* k_wb    = q_wb    + 1048576;
    u16* v_wb    = k_wb    + 1048576;
    u16* o_wb    = v_wb    + 1048576;
    u16* c2_wb   = o_wb    + 1048576;
    u16* c3_wb   = c2_wb   + 2097152;
    u16* ertb    = c3_wb   + 2097152;

    const dim3 blk256(256);
    const dim3 tgrid(32, 32, NB);
    const dim3 tblk(32, 8);
    const int EW = 16384;  // 4M / 256

    // --- weight casts ---
    cast_k<<<8192, blk256, 0, stream>>>(glu_w, glu_wb, 2097152);
    cast_k<<<4096, blk256, 0, stream>>>(c1L_pw, c1L_pwb, 1048576);
    cast_k<<<2048, blk256, 0, stream>>>(c1R_pw, c1R_pwb, 524288);
    cast_k<<<4096, blk256, 0, stream>>>(c1M_pw, c1M_pwb, 1048576);
    cast_k<<<4096, blk256, 0, stream>>>(q_w, q_wb, 1048576);
    cast_k<<<4096, blk256, 0, stream>>>(k_w, k_wb, 1048576);
    cast_k<<<4096, blk256, 0, stream>>>(v_w, v_wb, 1048576);
    cast_k<<<4096, blk256, 0, stream>>>(o_w, o_wb, 1048576);
    cast_k<<<8192, blk256, 0, stream>>>(c2_w, c2_wb, 2097152);
    cast_k<<<8192, blk256, 0, stream>>>(c3_w, c3_wb, 2097152);
    ercast_k<<<1024, blk256, 0, stream>>>(er, ertb);

    // 1. input projection
    inproj_k<<<tgrid, tblk, 0, stream>>>(src, in_w, X);
    // 2. h = ln1(x)
    ln_bf_k<<<4096, blk256, 0, stream>>>(X, Hbf, ln1_g, ln1_b);
    // 3. g = h @ glu_w^T  (4096x2048x1024) -> fp32
    gemm_bf<0, false, false><<<dim3(16, 32, 1), blk256, 0, stream>>>(
        Hbf, glu_wb, G, 1024, 1024, 1024, 2048, 0, 0, 0,
        nullptr, nullptr, 0, 0, 1.f);
    // 4. x += glu
    glu_k<<<EW, blk256, 0, stream>>>(G, X);
    // 5. h = ln2(x)
    ln_bf_k<<<4096, blk256, 0, stream>>>(X, Hbf, ln2_g, ln2_b);
    // 6-7. hL = relu(c1L_pw · dconvF(h)): transposed conv out -> NT GEMM
    dconvF_t_k<<<tgrid, blk256, 0, stream>>>(Hbf, T2bf, c1L_dw);
    gemm_bf<1, false, false><<<dim3(8, 8, NB), blk256, 0, stream>>>(
        c1L_pwb, T2bf, SB, 1024, 1024, 1024, 1024, 0, M1, M1,
        nullptr, nullptr, 0, 0, 1.f);
    // 8-9. SB[:, :512] += relu(dconvT(h) @ c1R_pw^T)
    dconvT_bf_k<<<EW, blk256, 0, stream>>>(Hbf, T1bf, c1R_dw, nullptr);
    gemm_bf<1, true, false><<<dim3(4, 32, 1), blk256, 0, stream>>>(
        T1bf, c1R_pwb, SB, 1024, 1024, 1024, 1024, 0, 0, 0,
        nullptr, nullptr, 0, 0, 1.f);
    // 10. h = ln3(SB)
    ln_bf_k<<<4096, blk256, 0, stream>>>(SB, Hbf, ln3_g, ln3_b);
    // 11-12. x += dconvT(h) @ c1M_pw^T
    dconvT_bf_k<<<EW, blk256, 0, stream>>>(Hbf, T1bf, c1M_dw, nullptr);
    gemm_bf<0, true, false><<<dim3(8, 32, 1), blk256, 0, stream>>>(
        T1bf, c1M_pwb, X, 1024, 1024, 1024, 1024, 0, 0, 0,
        nullptr, nullptr, 0, 0, 1.f);
    // 13. h = ln4(x)
    ln_bf_k<<<4096, blk256, 0, stream>>>(X, Hbf, ln4_g, ln4_b);
    // 14. Q/K/V
    gemm_bf<0, false, true><<<dim3(8, 32, 1), blk256, 0, stream>>>(
        Hbf, q_wb, T1bf, 1024, 1024, 1024, 1024, 0, 0, 0,
        q_b, nullptr, 0, 0, 1.f);
    dconvT_bf_k<<<EW, blk256, 0, stream>>>(T1bf, Qbf, qc_w, qc_b);
    gemm_bf<0, false, true><<<dim3(8, 32, 1), blk256, 0, stream>>>(
        Hbf, k_wb, T1bf, 1024, 1024, 1024, 1024, 0, 0, 0,
        k_b, nullptr, 0, 0, 1.f);
    dconvT_bf_k<<<EW, blk256, 0, stream>>>(T1bf, Kbf, qc_w, qc_b);
    gemm_bf<0, false, true><<<dim3(8, 32, 1), blk256, 0, stream>>>(
        Hbf, v_wb, T1bf, 1024, 1024, 1024, 1024, 0, 0, 0,
        v_b, nullptr, 0, 0, 1.f);
    dconvT_t_k<<<tgrid, blk256, 0, stream>>>(T1bf, Vt, qc_w, qc_b);

    // 15-18. attention per batch; AO -> T1bf (B,T,F)
    const float iscale = 0.03125f;  // 1/sqrt(1024)
    for (int b = 0; b < NB; b++) {
        const u16* Qx = Qbf + (long long)b * M1;
        const u16* Kx = Kbf + (long long)b * M1;
        const u16* Vx = Vt  + (long long)b * M1;
        u16* AOx = T1bf + (long long)b * M1;
        // P[band][t][j] = Q_band @ ert^T   (fp32)
        gemm_bf<0, false, false><<<dim3(8, 8, 4), blk256, 0, stream>>>(
            Qx, ertb, Pb, 256, 1024, 256, 1024, 256, 0, M1,
            nullptr, nullptr, 0, 0, 1.f);
        // S[band][i][j] = (Q·K^T + P^T)/32  -> bf16
        gemm_bf<0, false, true><<<dim3(8, 8, 4), blk256, 0, stream>>>(
            Qx, Kx, Sbf, 256, 1024, 1024, 1024, 256, 256, M1,
            nullptr, Pb, M1, 1024, iscale);
        softmax_bf_k<<<4096, blk256, 0, stream>>>(Sbf);
        // AO[t][band*256+d] = S @ Vt_band^T  -> bf16
        gemm_bf<0, false, true><<<dim3(2, 8, 4), blk256, 0, stream>>>(
            Sbf, Vx, AOx, 1024, 1024, 1024, 1024, M1, 256 * 1024, 256,
            nullptr, nullptr, 0, 0, 1.f);
    }
    // 19. x += AO @ o_w^T + o_b
    gemm_bf<0, true, false><<<dim3(8, 32, 1), blk256, 0, stream>>>(
        T1bf, o_wb, X, 1024, 1024, 1024, 1024, 0, 0, 0,
        o_b, nullptr, 0, 0, 1.f);
    // 20. h = ln5(x)
    ln_bf_k<<<4096, blk256, 0, stream>>>(X, Hbf, ln5_g, ln5_b);
    // 21. mid = relu(h @ c2_w^T)^2 -> bf16
    gemm_bf<2, false, true><<<dim3(16, 32, 1), blk256, 0, stream>>>(
        Hbf, c2_wb, Gbf, 1024, 1024, 1024, 2048, 0, 0, 0,
        nullptr, nullptr, 0, 0, 1.f);
    // 22. x += mid @ c3_w^T
    gemm_bf<0, true, false><<<dim3(8, 32, 1), blk256, 0, stream>>>(
        Gbf, c3_wb, X, 2048, 2048, 2048, 1024, 0, 0, 0,
        nullptr, nullptr, 0, 0, 1.f);
    // 23. output head
    out_k<<<tgrid, tblk, 0, stream>>>(src, X, out_w, out);
}

// Round 3
// 682.838 us; speedup vs baseline: 4.6217x; 1.4703x over previous
//
#include <hip/hip_runtime.h>
#include <math.h>

// ---------------------------------------------------------------------------
// FrameTransformer — occupancy round.
// Activations (B,T,F) row-major, B=4, T=F=1024. Residual X fp32; GEMM
// operands bf16, all NT-form. QKV fused (N=3072). Rel-pos folded into the
// S GEMM via K=512 concat: S = [Q|er^T] · [K|Q]^T / 32. BN=64 tiles for
// narrow GEMMs to double resident blocks.
// ---------------------------------------------------------------------------

typedef unsigned short u16;
typedef __attribute__((ext_vector_type(4))) float floatx4;
typedef __attribute__((ext_vector_type(8))) short short8;

#define NB 4
static const long long M1 = 1024LL * 1024LL;

__device__ __forceinline__ float bf2f(u16 h) {
    union { unsigned int u; float f; } v;
    v.u = ((unsigned int)h) << 16;
    return v.f;
}
__device__ __forceinline__ u16 f2bf(float x) {
    union { float f; unsigned int u; } v;
    v.f = x;
    unsigned int r = (v.u + 0x7FFFu + ((v.u >> 16) & 1u)) >> 16;
    return (u16)r;
}

__device__ __forceinline__ void async_cp16(const u16* g, u16* lds) {
    __builtin_amdgcn_global_load_lds(
        (const __attribute__((address_space(1))) unsigned int*)g,
        (__attribute__((address_space(3))) unsigned int*)lds, 16, 0, 0);
}

__device__ __forceinline__ float block_sum(float v) {
    __shared__ float sd[4];
    #pragma unroll
    for (int off = 32; off; off >>= 1) v += __shfl_down(v, off, 64);
    int lane = threadIdx.x & 63, wid = threadIdx.x >> 6;
    __syncthreads();
    if (lane == 0) sd[wid] = v;
    __syncthreads();
    return sd[0] + sd[1] + sd[2] + sd[3];
}
__device__ __forceinline__ float block_max(float v) {
    __shared__ float sd[4];
    #pragma unroll
    for (int off = 32; off; off >>= 1) v = fmaxf(v, __shfl_down(v, off, 64));
    int lane = threadIdx.x & 63, wid = threadIdx.x >> 6;
    __syncthreads();
    if (lane == 0) sd[wid] = v;
    __syncthreads();
    return fmaxf(fmaxf(sd[0], sd[1]), fmaxf(sd[2], sd[3]));
}

// ---------------------------------------------------------------------------
// bf16 NT GEMM: C[M,N] (op)= act( scale*(A·B^T + bias) )
// A [M,K] bf16, B [N,K] bf16, both row-major. Tile 128 x BN (BN=128 or 64),
// BK=32. 4 waves: wave m = (w>>1)*64, wave n = (w&1)*(BN/2).
// ACT: 0 none, 1 relu, 2 relu^2.  ACCUM: fp32 C += v.  OBF: write bf16.
// M mult of 128, N mult of BN, K mult of 32.
// ---------------------------------------------------------------------------
template<int BN, int ACT, bool ACCUM, bool OBF>
__global__ __launch_bounds__(256)
void gemm_bf(const u16* __restrict__ A, const u16* __restrict__ B,
             void* __restrict__ Cv, int K, int lda, int ldb, int ldc,
             long long sAz, long long sBz, long long sCz,
             const float* __restrict__ bias, float scale)
{
    constexpr int NJ = BN / 32;        // b-frags per wave
    constexpr int RB = BN / 64;        // B staging rounds

    A += (long long)blockIdx.z * sAz;
    B += (long long)blockIdx.z * sBz;
    const long long zc = (long long)blockIdx.z * sCz;

    __shared__ u16 As[128 * 32];
    __shared__ u16 Bs[BN * 32];

    const int tid  = threadIdx.x;
    const int lane = tid & 63;
    const int w    = tid >> 6;
    const int wm   = (w >> 1) * 64;
    const int wn   = (w & 1) * (BN / 2);
    const int m0   = blockIdx.y * 128;
    const int n0   = blockIdx.x * BN;

    const int srow = (lane >> 2);
    const int skq  = (lane & 3) * 8;

    floatx4 acc[4][NJ];
    #pragma unroll
    for (int i = 0; i < 4; i++)
        #pragma unroll
        for (int j = 0; j < NJ; j++)
            acc[i][j] = floatx4{0.f, 0.f, 0.f, 0.f};

    for (int k0 = 0; k0 < K; k0 += 32) {
        #pragma unroll
        for (int r = 0; r < 2; r++) {
            const int rowbase = r * 64 + w * 16;
            async_cp16(A + (long long)(m0 + rowbase + srow) * lda + k0 + skq,
                       &As[rowbase * 32]);
        }
        #pragma unroll
        for (int r = 0; r < RB; r++) {
            const int rowbase = r * 64 + w * 16;
            async_cp16(B + (long long)(n0 + rowbase + srow) * ldb + k0 + skq,
                       &Bs[rowbase * 32]);
        }
        __syncthreads();

        short8 a[4], b[NJ];
        const int fr = (lane & 15);
        const int fq = (lane >> 4) * 8;
        #pragma unroll
        for (int i = 0; i < 4; i++)
            a[i] = *(const short8*)&As[(wm + i * 16 + fr) * 32 + fq];
        #pragma unroll
        for (int j = 0; j < NJ; j++)
            b[j] = *(const short8*)&Bs[(wn + j * 16 + fr) * 32 + fq];
        #pragma unroll
        for (int i = 0; i < 4; i++)
            #pragma unroll
            for (int j = 0; j < NJ; j++)
                acc[i][j] = __builtin_amdgcn_mfma_f32_16x16x32_bf16(
                    a[i], b[j], acc[i][j], 0, 0, 0);
        __syncthreads();
    }

    float* Cf = (float*)Cv;
    u16*  Cb  = (u16*)Cv;
    const int cn    = n0 + wn + (lane & 15);
    const int rbase = m0 + wm + (lane >> 4) * 4;
    float bj[NJ];
    #pragma unroll
    for (int j = 0; j < NJ; j++) bj[j] = bias ? bias[cn + j * 16] : 0.f;

    #pragma unroll
    for (int i = 0; i < 4; i++) {
        #pragma unroll
        for (int r = 0; r < 4; r++) {
            const int m = rbase + i * 16 + r;
            #pragma unroll
            for (int j = 0; j < NJ; j++) {
                const int n = cn + j * 16;
                float v = (acc[i][j][r] + bj[j]) * scale;
                if (ACT == 1) v = fmaxf(v, 0.f);
                else if (ACT == 2) { v = fmaxf(v, 0.f); v = v * v; }
                const long long ci = zc + (long long)m * ldc + n;
                if (OBF)        Cb[ci] = f2bf(v);
                else if (ACCUM) Cf[ci] += v;
                else            Cf[ci] = v;
            }
        }
    }
}

// ---------------------------------------------------------------------------
__global__ __launch_bounds__(256)
void ln_bf_k(const float* __restrict__ in, u16* __restrict__ out,
             const float* __restrict__ g, const float* __restrict__ b)
{
    long long row = blockIdx.x;
    const float4* ip = (const float4*)(in + (row << 10));
    int tid = threadIdx.x;
    float4 v = ip[tid];
    float s = v.x + v.y + v.z + v.w;
    s = block_sum(s);
    float mean = s * (1.f / 1024.f);
    float dx = v.x - mean, dy = v.y - mean, dz = v.z - mean, dw = v.w - mean;
    float s2 = dx * dx + dy * dy + dz * dz + dw * dw;
    s2 = block_sum(s2);
    float inv = rsqrtf(s2 * (1.f / 1024.f) + 1e-5f);
    float4 gg = ((const float4*)g)[tid];
    float4 bb = ((const float4*)b)[tid];
    ushort4 o;
    o.x = f2bf(dx * inv * gg.x + bb.x);
    o.y = f2bf(dy * inv * gg.y + bb.y);
    o.z = f2bf(dz * inv * gg.z + bb.z);
    o.w = f2bf(dw * inv * gg.w + bb.w);
    ((ushort4*)(out + (row << 10)))[tid] = o;
}

__global__ __launch_bounds__(256)
void softmax_bf_k(u16* __restrict__ S)
{
    long long row = blockIdx.x;
    u16* p = S + (row << 10);
    int tid = threadIdx.x;
    ushort4 u = ((ushort4*)p)[tid];
    float x0 = bf2f(u.x), x1 = bf2f(u.y), x2 = bf2f(u.z), x3 = bf2f(u.w);
    float m = fmaxf(fmaxf(x0, x1), fmaxf(x2, x3));
    m = block_max(m);
    x0 = expf(x0 - m); x1 = expf(x1 - m); x2 = expf(x2 - m); x3 = expf(x3 - m);
    float s = x0 + x1 + x2 + x3;
    s = block_sum(s);
    float r = 1.f / s;
    u.x = f2bf(x0 * r); u.y = f2bf(x1 * r); u.z = f2bf(x2 * r); u.w = f2bf(x3 * r);
    ((ushort4*)p)[tid] = u;
}

__global__ __launch_bounds__(256)
void inproj_k(const float* __restrict__ src, const float* __restrict__ inw,
              float* __restrict__ X)
{
    __shared__ float tile[32][33];
    int b = blockIdx.z;
    int f0 = blockIdx.y * 32, t0 = blockIdx.x * 32;
    float w0 = inw[0], w1 = inw[1];
    for (int r = threadIdx.y; r < 32; r += 8) {
        int f = f0 + r, t = t0 + threadIdx.x;
        float s0 = src[(((long long)b * 2 + 0) * 1025 + f) * 1024 + t];
        float s1 = src[(((long long)b * 2 + 1) * 1025 + f) * 1024 + t];
        tile[r][threadIdx.x] = w0 * s0 + w1 * s1;
    }
    __syncthreads();
    for (int r = threadIdx.y; r < 32; r += 8)
        X[((long long)b * 1024 + t0 + r) * 1024 + f0 + threadIdx.x] = tile[threadIdx.x][r];
}

__global__ __launch_bounds__(256)
void glu_k(const float* __restrict__ G, float* __restrict__ X)
{
    int idx = blockIdx.x * 256 + threadIdx.x;
    int f = idx & 1023;
    long long row = idx >> 10;
    float a = G[row * 2048 + f];
    float s = G[row * 2048 + 1024 + f];
    X[idx] += a * (1.f / (1.f + expf(-s)));
}

// dconv along f (contiguous), channels=t, k=11 pad 5, transposed out[b][f][t].
__global__ __launch_bounds__(256)
void dconvF_t_k(const u16* __restrict__ in, u16* __restrict__ out,
                const float* __restrict__ w)
{
    __shared__ float itile[32][44];
    __shared__ float otile[32][33];
    int b = blockIdx.z, t0 = blockIdx.y * 32, f0 = blockIdx.x * 32;
    int tx = threadIdx.x & 31, ty = threadIdx.x >> 5;
    for (int r = ty; r < 32; r += 8)
        for (int c = tx; c < 42; c += 32) {
            int f = f0 - 5 + c;
            itile[r][c] = (f >= 0 && f < 1024)
                ? bf2f(in[((long long)(b * 1024 + t0 + r)) * 1024 + f]) : 0.f;
        }
    __syncthreads();
    for (int r = ty; r < 32; r += 8) {
        const float* wr = w + (t0 + r) * 11;
        float acc = 0.f;
        #pragma unroll
        for (int k = 0; k < 11; k++) acc += itile[r][tx + k] * wr[k];
        otile[tx][r] = acc;
    }
    __syncthreads();
    for (int r = ty; r < 32; r += 8)
        out[((long long)(b * 1024 + f0 + r)) * 1024 + t0 + tx] = f2bf(otile[r][tx]);
}

// dconv along t (strided), channels=f, k=7 pad 3, bf16 (B,T,F)->(B,T,F).
__global__ __launch_bounds__(256)
void dconvT_bf_k(const u16* __restrict__ in, u16* __restrict__ out,
                 const float* __restrict__ w)
{
    int idx = blockIdx.x * 256 + threadIdx.x;
    int f = idx & 1023;
    int bt = idx >> 10;
    int t = bt & 1023;
    int b = bt >> 10;
    const float* wr = w + f * 7;
    float acc = 0.f;
    #pragma unroll
    for (int k = 0; k < 7; k++) {
        int tt = t + k - 3;
        if (tt >= 0 && tt < 1024)
            acc += bf2f(in[(((long long)b << 10) + tt) * 1024 + f]) * wr[k];
    }
    out[idx] = f2bf(acc);
}

// V path: dconv along t on T3 v-plane (stride 3072, offset 2048) + bias,
// transposed out Vt[b][f][t].
__global__ __launch_bounds__(256)
void vconv_t_k(const u16* __restrict__ T3, u16* __restrict__ out,
               const float* __restrict__ w, const float* __restrict__ bias)
{
    __shared__ float itile[38][32];
    __shared__ float otile[32][33];
    int b = blockIdx.z, t0 = blockIdx.y * 32, f0 = blockIdx.x * 32;
    int tx = threadIdx.x & 31, ty = threadIdx.x >> 5;
    for (int i = threadIdx.x; i < 38 * 32; i += 256) {
        int r = i >> 5, c = i & 31;
        int t = t0 - 3 + r;
        itile[r][c] = (t >= 0 && t < 1024)
            ? bf2f(T3[((long long)(b * 1024 + t)) * 3072 + 2048 + f0 + c]) : 0.f;
    }
    __syncthreads();
    for (int r = ty; r < 32; r += 8) {
        const float* wr = w + (f0 + tx) * 7;
        float acc = bias[f0 + tx];
        #pragma unroll
        for (int k = 0; k < 7; k++) acc += itile[r + k][tx] * wr[k];
        otile[tx][r] = acc;
    }
    __syncthreads();
    for (int r = ty; r < 32; r += 8)
        out[((long long)(b * 1024 + f0 + r)) * 1024 + t0 + tx] = f2bf(otile[r][tx]);
}

// Q/K path: dconv along t on T3 q,k planes + pack S-GEMM operands:
//   Apk[z][t][0:256]=qc_q  Apk[z][t][256:512]=er^T[t]
//   Bpk[z][t][0:256]=qc_k  Bpk[z][t][256:512]=qc_q     (z = b*4+band)
__global__ __launch_bounds__(256)
void qkpack_k(const u16* __restrict__ T3, const float* __restrict__ w,
              const float* __restrict__ bias, const u16* __restrict__ ertb,
              u16* __restrict__ Apk, u16* __restrict__ Bpk)
{
    int idx = blockIdx.x * 256 + threadIdx.x;  // 4M
    int f = idx & 1023;
    int t = (idx >> 10) & 1023;
    int b = idx >> 20;
    int band = f >> 8, d = f & 255, z = (b << 2) | band;
    const float* wr = w + f * 7;
    float bq = bias[f];
    float aq = bq, ak = bq;
    #pragma unroll
    for (int k = 0; k < 7; k++) {
        int tt = t + k - 3;
        if (tt >= 0 && tt < 1024) {
            const u16* row = T3 + ((long long)(b << 10) + tt) * 3072 + f;
            float wk = wr[k];
            aq += bf2f(row[0]) * wk;
            ak += bf2f(row[1024]) * wk;
        }
    }
    long long base = (long long)z * 524288 + t * 512 + d;
    u16 qb = f2bf(aq);
    Apk[base] = qb;
    Apk[base + 256] = ertb[t * 256 + d];
    Bpk[base] = f2bf(ak);
    Bpk[base + 256] = qb;
}

// AOz (z,t,d) -> AO (b,t,f=band*256+d)
__global__ __launch_bounds__(256)
void aorepack_k(const u16* __restrict__ AOz, u16* __restrict__ AO)
{
    int idx = blockIdx.x * 256 + threadIdx.x;  // 4M
    int d = idx & 255;
    int t = (idx >> 8) & 1023;
    int z = idx >> 18;
    int b = z >> 2, band = z & 3;
    AO[((((long long)b << 10) + t) << 10) + (band << 8) + d] = AOz[idx];
}

// Fused weight cast: 10 fp32 sources -> contiguous bf16 W0.
struct CastArgs { const float* s[10]; };
__global__ __launch_bounds__(256)
void castall_k(CastArgs a, u16* __restrict__ dst)
{
    const int sz[10] = {2097152, 1048576, 524288, 1048576, 1048576,
                        1048576, 1048576, 1048576, 2097152, 2097152};
    int seg = blockIdx.y;
    int n = sz[seg];
    int base = 0;
    for (int i = 0; i < seg; i++) base += sz[i];
    int i4 = (blockIdx.x * 256 + threadIdx.x) * 4;
    if (i4 >= n) return;
    float4 v = *(const float4*)(a.s[seg] + i4);
    ushort4 o;
    o.x = f2bf(v.x); o.y = f2bf(v.y); o.z = f2bf(v.z); o.w = f2bf(v.w);
    *(ushort4*)(dst + base + i4) = o;
}

// er (256,1024) -> ert (1024,256) bf16
__global__ __launch_bounds__(256)
void ercast_k(const float* __restrict__ er, u16* __restrict__ ert)
{
    int idx = blockIdx.x * 256 + threadIdx.x;
    int j = idx >> 8, d = idx & 255;
    ert[idx] = f2bf(er[d * 1024 + j]);
}

// concat q_b,k_b,v_b -> qkvb (3072 fp32)
__global__ __launch_bounds__(256)
void biascat_k(const float* __restrict__ qb, const float* __restrict__ kb,
               const float* __restrict__ vb, float* __restrict__ dst)
{
    int i = blockIdx.x * 256 + threadIdx.x;
    if (i < 1024) dst[i] = qb[i];
    else if (i < 2048) dst[i] = kb[i - 1024];
    else if (i < 3072) dst[i] = vb[i - 2048];
}

__global__ __launch_bounds__(256)
void out_k(const float* __restrict__ src, const float* __restrict__ X,
           const float* __restrict__ ow, float* __restrict__ out)
{
    __shared__ float tile[32][33];
    int b = blockIdx.z;
    int f0 = blockIdx.y * 32, t0 = blockIdx.x * 32;
    for (int r = threadIdx.y; r < 32; r += 8)
        tile[r][threadIdx.x] = X[((long long)b * 1024 + t0 + r) * 1024 + f0 + threadIdx.x];
    __syncthreads();
    float w00 = ow[0], w01 = ow[1], w02 = ow[2];
    float w10 = ow[3], w11 = ow[4], w12 = ow[5];
    for (int r = threadIdx.y; r < 32; r += 8) {
        int f = f0 + r, t = t0 + threadIdx.x;
        float s0 = src[(((long long)b * 2 + 0) * 1025 + f) * 1024 + t];
        float s1 = src[(((long long)b * 2 + 1) * 1025 + f) * 1024 + t];
        float xv = tile[threadIdx.x][r];
        float v0 = fminf(fmaxf(w00 * s0 + w01 * s1 + w02 * xv, 0.f), 6.f) * (1.f / 6.f);
        float v1 = fminf(fmaxf(w10 * s0 + w11 * s1 + w12 * xv, 0.f), 6.f) * (1.f / 6.f);
        out[(((long long)b * 2 + 0) * 1025 + f) * 1024 + t] = v0;
        out[(((long long)b * 2 + 1) * 1025 + f) * 1024 + t] = v1;
        if (f == 1023) {
            out[(((long long)b * 2 + 0) * 1025 + 1024) * 1024 + t] = v0;
            out[(((long long)b * 2 + 1) * 1025 + 1024) * 1024 + t] = v1;
        }
    }
}

// ---------------------------------------------------------------------------
extern "C" void kernel_launch(void* const* d_in, const int* in_sizes, int n_in,
                              void* d_out, int out_size, void* d_ws, size_t ws_size,
                              hipStream_t stream)
{
    const float* src    = (const float*)d_in[0];
    const float* in_w   = (const float*)d_in[1];
    const float* ln1_g  = (const float*)d_in[2];
    const float* ln1_b  = (const float*)d_in[3];
    const float* glu_w  = (const float*)d_in[4];
    const float* ln2_g  = (const float*)d_in[5];
    const float* ln2_b  = (const float*)d_in[6];
    const float* c1L_dw = (const float*)d_in[7];
    const float* c1L_pw = (const float*)d_in[8];
    const float* c1R_dw = (const float*)d_in[9];
    const float* c1R_pw = (const float*)d_in[10];
    const float* ln3_g  = (const float*)d_in[11];
    const float* ln3_b  = (const float*)d_in[12];
    const float* c1M_dw = (const float*)d_in[13];
    const float* c1M_pw = (const float*)d_in[14];
    const float* ln4_g  = (const float*)d_in[15];
    const float* ln4_b  = (const float*)d_in[16];
    const float* q_w    = (const float*)d_in[17];
    const float* q_b    = (const float*)d_in[18];
    const float* qc_w   = (const float*)d_in[19];
    const float* qc_b   = (const float*)d_in[20];
    const float* k_w    = (const float*)d_in[21];
    const float* k_b    = (const float*)d_in[22];
    const float* v_w    = (const float*)d_in[23];
    const float* v_b    = (const float*)d_in[24];
    const float* o_w    = (const float*)d_in[25];
    const float* o_b    = (const float*)d_in[26];
    const float* er     = (const float*)d_in[27];
    const float* ln5_g  = (const float*)d_in[28];
    const float* ln5_b  = (const float*)d_in[29];
    const float* c2_w   = (const float*)d_in[30];
    const float* c3_w   = (const float*)d_in[31];
    const float* out_w  = (const float*)d_in[32];
    float* out = (float*)d_out;

    const size_t MB = 1ull << 20;
    if (ws_size < 162 * MB) return;
    char* wsb = (char*)d_ws;
    float* X   = (float*)(wsb + 0);         // 16 MB fp32 residual
    float* SB  = (float*)(wsb + 16 * MB);   // 16 MB fp32 hL+hR
    float* G   = (float*)(wsb + 32 * MB);   // 32 MB fp32 glu out
    u16* Apk   = (u16*)(wsb + 32 * MB);     // reuse: 16 MB S-GEMM A' (z,t,512)
    u16* Bpk   = (u16*)(wsb + 48 * MB);     //        16 MB S-GEMM B'
    u16* Hbf   = (u16*)(wsb + 64 * MB);     // 8 MB ln outputs
    u16* T1bf  = (u16*)(wsb + 72 * MB);     // 8 MB dconv temps (pre-QKV)
    u16* T3    = (u16*)(wsb + 72 * MB);     // 24 MB QKV (4096x3072)
    u16* AOz   = (u16*)(wsb + 72 * MB);     // reuse: 8 MB AO (z,t,256)
    u16* AO    = (u16*)(wsb + 80 * MB);     // reuse: 8 MB AO (B,T,F)
    u16* T2bf  = (u16*)(wsb + 96 * MB);     // 8 MB dconvF out (c1L)
    u16* Vt    = (u16*)(wsb + 96 * MB);     // reuse: 8 MB V^T (b,f,t)
    u16* Sbf   = (u16*)(wsb + 104 * MB);    // 32 MB scores (16,1024,1024)
    u16* Gbf   = (u16*)(wsb + 104 * MB);    // reuse: 16 MB ffn mid
    u16* W0    = (u16*)(wsb + 136 * MB);    // bf16 weights

    u16* glu_wb  = W0;
    u16* c1L_pwb = W0 + 2097152;
    u16* c1R_pwb = W0 + 3145728;
    u16* c1M_pwb = W0 + 3670016;
    u16* qkv_wb  = W0 + 4718592;   // q,k,v contiguous (3072 x 1024)
    u16* o_wb    = W0 + 7864320;
    u16* c2_wb   = W0 + 8912896;
    u16* c3_wb   = W0 + 11010048;
    u16* ertb    = W0 + 13107200;  // 262144
    float* qkvb  = (float*)(W0 + 13369344);  // 3072 fp32

    const dim3 blk256(256);
    const dim3 tgrid(32, 32, NB);
    const dim3 tblk(32, 8);
    const int EW = 16384;  // 4M / 256

    // --- weights ---
    CastArgs ca;
    ca.s[0] = glu_w;  ca.s[1] = c1L_pw; ca.s[2] = c1R_pw; ca.s[3] = c1M_pw;
    ca.s[4] = q_w;    ca.s[5] = k_w;    ca.s[6] = v_w;    ca.s[7] = o_w;
    ca.s[8] = c2_w;   ca.s[9] = c3_w;
    castall_k<<<dim3(2048, 10), blk256, 0, stream>>>(ca, W0);
    ercast_k<<<1024, blk256, 0, stream>>>(er, ertb);
    biascat_k<<<12, blk256, 0, stream>>>(q_b, k_b, v_b, qkvb);

    // 1. input projection
    inproj_k<<<tgrid, tblk, 0, stream>>>(src, in_w, X);
    // 2-3. h = ln1(x); g = h @ glu_w^T (4096x2048x1024)
    ln_bf_k<<<4096, blk256, 0, stream>>>(X, Hbf, ln1_g, ln1_b);
    gemm_bf<64, 0, false, false><<<dim3(32, 32, 1), blk256, 0, stream>>>(
        Hbf, glu_wb, G, 1024, 1024, 1024, 2048, 0, 0, 0, nullptr, 1.f);
    // 4. x += glu
    glu_k<<<EW, blk256, 0, stream>>>(G, X);
    // 5. h = ln2(x)
    ln_bf_k<<<4096, blk256, 0, stream>>>(X, Hbf, ln2_g, ln2_b);
    // 6-7. hL = relu(c1L_pw · dconvF(h))
    dconvF_t_k<<<tgrid, blk256, 0, stream>>>(Hbf, T2bf, c1L_dw);
    gemm_bf<64, 1, false, false><<<dim3(16, 8, NB), blk256, 0, stream>>>(
        c1L_pwb, T2bf, SB, 1024, 1024, 1024, 1024, 0, M1, M1, nullptr, 1.f);
    // 8-9. SB[:, :512] += relu(dconvT(h) @ c1R_pw^T)
    dconvT_bf_k<<<EW, blk256, 0, stream>>>(Hbf, T1bf, c1R_dw);
    gemm_bf<64, 1, true, false><<<dim3(8, 32, 1), blk256, 0, stream>>>(
        T1bf, c1R_pwb, SB, 1024, 1024, 1024, 1024, 0, 0, 0, nullptr, 1.f);
    // 10-12. h = ln3(SB); x += dconvT(h) @ c1M_pw^T
    ln_bf_k<<<4096, blk256, 0, stream>>>(SB, Hbf, ln3_g, ln3_b);
    dconvT_bf_k<<<EW, blk256, 0, stream>>>(Hbf, T1bf, c1M_dw);
    gemm_bf<64, 0, true, false><<<dim3(16, 32, 1), blk256, 0, stream>>>(
        T1bf, c1M_pwb, X, 1024, 1024, 1024, 1024, 0, 0, 0, nullptr, 1.f);
    // 13. h = ln4(x)
    ln_bf_k<<<4096, blk256, 0, stream>>>(X, Hbf, ln4_g, ln4_b);
    // 14. fused QKV GEMM (4096 x 3072 x 1024) -> T3 bf16
    gemm_bf<128, 0, false, true><<<dim3(24, 32, 1), blk256, 0, stream>>>(
        Hbf, qkv_wb, T3, 1024, 1024, 1024, 3072, 0, 0, 0, qkvb, 1.f);
    // 15-16. qc convs: pack S operands; V transposed
    qkpack_k<<<EW, blk256, 0, stream>>>(T3, qc_w, qc_b, ertb, Apk, Bpk);
    vconv_t_k<<<tgrid, blk256, 0, stream>>>(T3, Vt, qc_w, qc_b);
    // 17. S = (QK^T + rel-pos)/32, all 16 (b,band) planes, K=512
    gemm_bf<128, 0, false, true><<<dim3(8, 8, 16), blk256, 0, stream>>>(
        Apk, Bpk, Sbf, 512, 512, 512, 1024, 524288, 524288, M1,
        nullptr, 0.03125f);
    // 18. softmax (16384 rows)
    softmax_bf_k<<<16384, blk256, 0, stream>>>(Sbf);
    // 19-20. AO = S @ V  (per z: 1024 x 256 x 1024), repack to (B,T,F)
    gemm_bf<64, 0, false, true><<<dim3(4, 8, 16), blk256, 0, stream>>>(
        Sbf, Vt, AOz, 1024, 1024, 1024, 256, M1, 262144, 262144,
        nullptr, 1.f);
    aorepack_k<<<EW, blk256, 0, stream>>>(AOz, AO);
    // 21. x += AO @ o_w^T + o_b
    gemm_bf<64, 0, true, false><<<dim3(16, 32, 1), blk256, 0, stream>>>(
        AO, o_wb, X, 1024, 1024, 1024, 1024, 0, 0, 0, o_b, 1.f);
    // 22-23. h = ln5(x); mid = relu(h @ c2_w^T)^2
    ln_bf_k<<<4096, blk256, 0, stream>>>(X, Hbf, ln5_g, ln5_b);
    gemm_bf<64, 2, false, true><<<dim3(32, 32, 1), blk256, 0, stream>>>(
        Hbf, c2_wb, Gbf, 1024, 1024, 1024, 2048, 0, 0, 0, nullptr, 1.f);
    // 24. x += mid @ c3_w^T
    gemm_bf<64, 0, true, false><<<dim3(16, 32, 1), blk256, 0, stream>>>(
        Gbf, c3_wb, X, 2048, 2048, 2048, 1024, 0, 0, 0, nullptr, 1.f);
    // 25. output head
    out_k<<<tgrid, tblk, 0, stream>>>(src, X, out_w, out);
}